// Round 13
// baseline (3769.076 us; speedup 1.0000x reference)
//
#include <hip/hip_runtime.h>

#define NR 512
#define NI 128
#define B 32
#define T 1000
#define KC 256   // OpenBLAS level3 driver K-panel REBALANCING: for K=512 and
                 // GEMM_Q in (256,512] (haswell/zen Q=384, skylakex Q=320 alike),
                 // min_l = (512+1)/2 -> panels [0,256)+[256,512).
// Numeric model of the harness's numpy reference:
//  - input GEMM (einsum -> tensordot/BLAS, K=128 <= Q): per C element a single
//    ascending-k FMA chain (sgemm microkernel, one accumulator per element).
//  - z @ w_rec_masked: OpenBLAS sgemm, K=512 -> two 256-wide ascending-k FMA
//    chains (panel rebalancing), joined through C memory by one rounded add.
//    Binary z: fma(1,w,acc)=fl(acc+w), fma(0,w,acc)=acc -> only active rows
//    contribute; masked diagonal contributes exact +/-0 in-chain -> skip.
//  - elementwise: separate rounded f32 ufunc ops ((f32(decay)*v) + i_t) - z.

// Bare fp32 product with a compiler barrier so -ffp-contract=fast cannot fuse
// it into a neighboring add.
__device__ __forceinline__ float mul_nofma(float a, float b) {
    float r = a * b;
    asm volatile("" : "+v"(r));
    return r;
}

// ---------------- Kernel 1: i_in = inputs @ w_in -> voltages region of d_out
// Single ascending-i FMA chain per element (BLAS microkernel, K=128 one panel).
template <int ROWS>
__global__ __launch_bounds__(512) void k_in_gemm(const float* __restrict__ inputs,
                                                 const float* __restrict__ w_in,
                                                 float* __restrict__ i_in) {
    const int u = threadIdx.x;
    const int r0 = blockIdx.x * ROWS;
    float acc[ROWS];
#pragma unroll
    for (int r = 0; r < ROWS; ++r) acc[r] = 0.f;
    const float* __restrict__ inp = inputs + (long)r0 * NI;
#pragma unroll 4
    for (int i = 0; i < NI; ++i) {
        float w = w_in[i * NR + u];
#pragma unroll
        for (int r = 0; r < ROWS; ++r)
            acc[r] = __builtin_fmaf(inp[r * NI + i], w, acc[r]);   // ascending i, FMA
    }
#pragma unroll
    for (int r = 0; r < ROWS; ++r)
        i_in[(long)(r0 + r) * NR + u] = acc[r];
}

// ---------------- Kernel 2: per-batch LIF scan replicating np fp32 rounding.
// 32 blocks (one per batch) x 512 threads (one per neuron).
__global__ __launch_bounds__(512) void k_scan(const float* __restrict__ w_rec,
                                              const float* __restrict__ w_out,
                                              const float* __restrict__ b_out,
                                              float* __restrict__ out) {
    const int b = blockIdx.x;
    const int u = threadIdx.x;
    const int wav = u >> 6, lane = u & 63;

    float* __restrict__ volt_b = out + (long)b * (T * NR);                 // also i_in (in-place)
    float* __restrict__ spk_b  = out + (long)B * T * NR + (long)b * (T * NR);
    float* __restrict__ pred   = out + 2L * B * T * NR;

    __shared__ __align__(16) int list[NR];
    __shared__ int wcnt[8];
    __shared__ double projp[8];

    float v = 0.f, z = 0.f;
    const float decay = 0.951229424500714f;   // f32 rounding of the python scalar
    const double wo = (double)w_out[u];
    const double bo = (double)b_out[0];
    double ema = 0.0;

    for (int t = 0; t < T; ++t) {
        // ---- compact active (z==1) indices into LDS list, ascending order
        unsigned long long m = __ballot(z > 0.5f);
        if (lane == 0) wcnt[wav] = __popcll(m);
        __syncthreads();
        int cnt = 0, base = 0;
#pragma unroll
        for (int w2 = 0; w2 < 8; ++w2) {
            int c = wcnt[w2];
            if (w2 < wav) base += c;
            cnt += c;
        }
        if (z > 0.5f) {
            int pos = base + __popcll(m & ((1ull << lane) - 1ull));
            list[pos] = u;
        }
        float ii = volt_b[t * NR + u];   // i_in staged here by k_in_gemm
        __syncthreads();

        // ---- recurrent term: two ascending-k fp32 chains, panels [0,256)+[256,512),
        // joined by one rounded add (OpenBLAS K-panel accumulation through C).
        // Active-row skip & in-chain diagonal zero are bit-exact equivalences.
        float s1 = 0.f, s2 = 0.f;
        int k = 0;
        for (; k + 8 <= cnt; k += 8) {
            int4 ja = *(const int4*)&list[k];
            int4 jb = *(const int4*)&list[k + 4];
            int j0 = __builtin_amdgcn_readfirstlane(ja.x);
            int j1 = __builtin_amdgcn_readfirstlane(ja.y);
            int j2 = __builtin_amdgcn_readfirstlane(ja.z);
            int j3 = __builtin_amdgcn_readfirstlane(ja.w);
            int j4 = __builtin_amdgcn_readfirstlane(jb.x);
            int j5 = __builtin_amdgcn_readfirstlane(jb.y);
            int j6 = __builtin_amdgcn_readfirstlane(jb.z);
            int j7 = __builtin_amdgcn_readfirstlane(jb.w);
            float w0 = w_rec[j0 * NR + u]; if (j0 == u) w0 = 0.f;
            float w1 = w_rec[j1 * NR + u]; if (j1 == u) w1 = 0.f;
            float w2 = w_rec[j2 * NR + u]; if (j2 == u) w2 = 0.f;
            float w3 = w_rec[j3 * NR + u]; if (j3 == u) w3 = 0.f;
            float w4 = w_rec[j4 * NR + u]; if (j4 == u) w4 = 0.f;
            float w5 = w_rec[j5 * NR + u]; if (j5 == u) w5 = 0.f;
            float w6 = w_rec[j6 * NR + u]; if (j6 == u) w6 = 0.f;
            float w7 = w_rec[j7 * NR + u]; if (j7 == u) w7 = 0.f;
            if (j0 < KC) s1 = __fadd_rn(s1, w0); else s2 = __fadd_rn(s2, w0);
            if (j1 < KC) s1 = __fadd_rn(s1, w1); else s2 = __fadd_rn(s2, w1);
            if (j2 < KC) s1 = __fadd_rn(s1, w2); else s2 = __fadd_rn(s2, w2);
            if (j3 < KC) s1 = __fadd_rn(s1, w3); else s2 = __fadd_rn(s2, w3);
            if (j4 < KC) s1 = __fadd_rn(s1, w4); else s2 = __fadd_rn(s2, w4);
            if (j5 < KC) s1 = __fadd_rn(s1, w5); else s2 = __fadd_rn(s2, w5);
            if (j6 < KC) s1 = __fadd_rn(s1, w6); else s2 = __fadd_rn(s2, w6);
            if (j7 < KC) s1 = __fadd_rn(s1, w7); else s2 = __fadd_rn(s2, w7);
        }
        for (; k < cnt; ++k) {
            int j = __builtin_amdgcn_readfirstlane(list[k]);
            float w = w_rec[j * NR + u];
            if (j == u) w = 0.f;
            if (j < KC) s1 = __fadd_rn(s1, w); else s2 = __fadd_rn(s2, w);
        }
        float rec = __fadd_rn(s1, s2);

        // ---- LIF update with np's exact op order, no FMA contraction:
        // i_t = ii + rec ; v' = (decay*v + i_t) - z
        float it = __fadd_rn(ii, rec);
        float m1 = mul_nofma(decay, v);
        float t2 = __fadd_rn(m1, it);
        float vn = __fsub_rn(t2, z);
        float zn = (vn > 1.0f) ? 1.0f : 0.0f;
        volt_b[t * NR + u] = vn;
        spk_b[t * NR + u]  = zn;

        // ---- output projection + EMA (loose tolerance: fp64 is fine)
        double p = (double)zn * wo;
#pragma unroll
        for (int o = 32; o > 0; o >>= 1) p += __shfl_xor(p, o, 64);
        if (lane == 0) projp[wav] = p;
        __syncthreads();                 // also protects list/wcnt before next step
        if (u == 0) {
            double pr = bo;
#pragma unroll
            for (int w2 = 0; w2 < 8; ++w2) pr += projp[w2];
            ema = 0.8 * ema + 0.2 * pr;
            pred[b * T + t] = (float)ema;
        }
        v = vn; z = zn;
    }
}

extern "C" void kernel_launch(void* const* d_in, const int* in_sizes, int n_in,
                              void* d_out, int out_size, void* d_ws, size_t ws_size,
                              hipStream_t stream) {
    const float* inputs = (const float*)d_in[0];
    const float* w_in   = (const float*)d_in[1];
    const float* w_rec  = (const float*)d_in[2];
    const float* w_out  = (const float*)d_in[3];
    const float* b_out  = (const float*)d_in[4];
    float* out = (float*)d_out;

    k_in_gemm<16><<<dim3(B * T / 16), dim3(512), 0, stream>>>(inputs, w_in, out);
    k_scan<<<dim3(B), dim3(512), 0, stream>>>(w_rec, w_out, b_out, out);
}